// Round 3
// baseline (464.209 us; speedup 1.0000x reference)
//
#include <hip/hip_runtime.h>

// EdgeBlock: out = relu(concat(node[snd], node[rcv], edge) @ w1 + b1) @ w2 + b2
// E=800000, N=50000, D=128. fp32 in/out, fp16 MFMA.
// Persistent waves, continuous gather ring (6-deep, wraps across tiles),
// w1^T swizzled in LDS, per-wave h roundtrip, waves_per_eu(2,2).

#define NE 800000
#define DD 128
#define NWTILE 25000   // wave-tiles of 32 edges
#define WSTRIDE 2048   // 256 blocks * 8 waves

typedef float f32x4v __attribute__((ext_vector_type(4)));
typedef float f32x16 __attribute__((ext_vector_type(16)));
typedef _Float16 f16x8 __attribute__((ext_vector_type(8)));

__device__ __forceinline__ f16x8 cvt8(f32x4v lo, f32x4v hi) {
    f16x8 r;
    r[0] = (_Float16)lo[0]; r[1] = (_Float16)lo[1];
    r[2] = (_Float16)lo[2]; r[3] = (_Float16)lo[3];
    r[4] = (_Float16)hi[0]; r[5] = (_Float16)hi[1];
    r[6] = (_Float16)hi[2]; r[7] = (_Float16)hi[3];
    return r;
}

// w1[384][128] -> w1t swizzled fp16: byte = col*768 + ((k*2) ^ ((col&15)<<4))
// w2[128][128] -> w2t fp16 [col][k] linear
__global__ void prep_w(const float* __restrict__ w1, const float* __restrict__ w2,
                       _Float16* __restrict__ w1t, _Float16* __restrict__ w2t) {
    int i = blockIdx.x * 256 + threadIdx.x;   // 65536 total
    if (i < 384 * 128) {
        int col = i / 384;
        int k = i - col * 384;
        float v = w1[(size_t)k * 128 + col];
        int byteoff = col * 768 + ((k * 2) ^ ((col & 15) << 4));
        *(_Float16*)((char*)w1t + byteoff) = (_Float16)v;
    } else {
        int j = i - 384 * 128;
        int col = j >> 7;
        int k = j & 127;
        w2t[j] = (_Float16)w2[(size_t)k * 128 + col];
    }
}

__global__ __attribute__((amdgpu_flat_work_group_size(512, 512),
                          amdgpu_waves_per_eu(2, 2)))
void edge_mlp(
    const float* __restrict__ node_attr,
    const int* __restrict__ eidx,
    const float* __restrict__ edge_attr,
    const _Float16* __restrict__ w1t,   // swizzled, 96KB
    const float* __restrict__ b1,
    const _Float16* __restrict__ w2t,   // linear [col][k], 32KB
    const float* __restrict__ b2,
    float* __restrict__ out) {
    extern __shared__ char lds[];   // [0,96K): w1t swz   [96K + wid*8K): h per wave

    const int tid = threadIdx.x;
    const int wid = tid >> 6;
    const int lane = tid & 63;
    const int r31 = lane & 31;
    const int g2 = lane >> 5;

    // ---- stage w1t -> LDS once per (persistent) block ----
    {
        const char* src = (const char*)w1t;
        #pragma unroll
        for (int i = 0; i < 12; i++) {
            int off = (tid + i * 512) * 16;   // 512*12*16B = 96KB
            *(f16x8*)(lds + off) = *(const f16x8*)(src + off);
        }
    }

    float b1v[4], b2v[4];
    #pragma unroll
    for (int n = 0; n < 4; n++) { b1v[n] = b1[n * 32 + r31]; b2v[n] = b2[n * 32 + r31]; }

    __syncthreads();   // the only block-wide sync; waves free-run after this

    char* hw = lds + 96 * 1024 + wid * 8192;
    const int xh = (r31 & 15) << 4;          // h read-side XOR
    const int xb[4] = { ((0 * 32 + r31) & 15) << 4, ((1 * 32 + r31) & 15) << 4,
                        ((2 * 32 + r31) & 15) << 4, ((3 * 32 + r31) & 15) << 4 };

    int g = blockIdx.x * 8 + wid;
    int e0 = g * 32 + r31;
    int snd = eidx[e0];
    int rcv = eidx[NE + e0];

    // continuous A-chunk ring: chunk c of tile = 8 fp32 at seg base + (c&7)*16 + g2*8
    f32x4v ring[6][2];
    {
        const float* bS = node_attr + (size_t)snd * DD;
        #pragma unroll
        for (int j = 0; j < 6; j++) {
            const float* p = bS + j * 16 + g2 * 8;
            ring[j][0] = *(const f32x4v*)p;
            ring[j][1] = *(const f32x4v*)(p + 4);
        }
    }

    while (g < NWTILE) {
        const int e = g * 32 + r31;
        const float* bS = node_attr + (size_t)snd * DD;
        const float* bR = node_attr + (size_t)rcv * DD;
        const float* bE = edge_attr + (size_t)e * DD;

        // prefetch next tile's indices a full tile ahead
        const int gn = g + WSTRIDE;
        const int gcl = (gn < NWTILE) ? gn : g;
        const int en = gcl * 32 + r31;
        const int snd_n = eidx[en];
        const int rcv_n = eidx[NE + en];

        // ---------------- GEMM1: 24-chunk stream, ring refill 6 ahead ----------------
        f32x16 acc[4] = {};
        #pragma unroll
        for (int c = 0; c < 24; c++) {
            const int slot = c % 6;
            f16x8 a = cvt8(ring[slot][0], ring[slot][1]);
            // refill slot with chunk c+6 (cn>=24 wraps into NEXT tile's sender seg)
            {
                const int cn = c + 6;
                const float* nb = (cn < 8) ? bS : (cn < 16) ? bR : (cn < 24) ? bE
                                   : (node_attr + (size_t)snd_n * DD);
                const float* p = nb + (cn & 7) * 16 + g2 * 8;
                ring[slot][0] = *(const f32x4v*)p;
                ring[slot][1] = *(const f32x4v*)(p + 4);
            }
            const int kb = c * 32 + g2 * 16;
            #pragma unroll
            for (int n = 0; n < 4; n++) {
                const int col = n * 32 + r31;
                f16x8 b = *(const f16x8*)(lds + col * 768 + (kb ^ xb[n]));
                acc[n] = __builtin_amdgcn_mfma_f32_32x32x16_f16(a, b, acc[n], 0, 0, 0);
            }
        }

        // ---- issue GEMM2 B-frags half 0 (hidden under h-write) ----
        f16x8 b2f0[4][4];
        #pragma unroll
        for (int kk = 0; kk < 4; kk++)
            #pragma unroll
            for (int n = 0; n < 4; n++)
                b2f0[kk][n] = *(const f16x8*)(w2t + (size_t)(n * 32 + r31) * 128 + kk * 16 + g2 * 8);

        // ---- bias + relu, h -> LDS fp16 (XOR-swizzled) ----
        #pragma unroll
        for (int n = 0; n < 4; n++) {
            const int col = n * 32 + r31;
            #pragma unroll
            for (int reg = 0; reg < 16; reg++) {
                const int row = (reg & 3) + 8 * (reg >> 2) + 4 * g2;
                float v = fmaxf(acc[n][reg] + b1v[n], 0.0f);
                const int byteoff = row * 256 + ((col * 2) ^ ((row & 15) << 4));
                *(_Float16*)(hw + byteoff) = (_Float16)v;
            }
        }

        // ---------------- GEMM2: [32x128] @ [128x128], two b2f halves ----------------
        f32x16 acc2[4] = {};
        #pragma unroll
        for (int kk = 0; kk < 4; kk++) {
            const int kb = kk * 32 + g2 * 16;
            f16x8 a = *(const f16x8*)(hw + r31 * 256 + (kb ^ xh));
            #pragma unroll
            for (int n = 0; n < 4; n++)
                acc2[n] = __builtin_amdgcn_mfma_f32_32x32x16_f16(a, b2f0[kk][n], acc2[n], 0, 0, 0);
        }
        f16x8 b2f1[4][4];
        #pragma unroll
        for (int kk = 0; kk < 4; kk++)
            #pragma unroll
            for (int n = 0; n < 4; n++)
                b2f1[kk][n] = *(const f16x8*)(w2t + (size_t)(n * 32 + r31) * 128 + (kk + 4) * 16 + g2 * 8);
        #pragma unroll
        for (int kk = 4; kk < 8; kk++) {
            const int kb = kk * 32 + g2 * 16;
            f16x8 a = *(const f16x8*)(hw + r31 * 256 + (kb ^ xh));
            #pragma unroll
            for (int n = 0; n < 4; n++)
                acc2[n] = __builtin_amdgcn_mfma_f32_32x32x16_f16(a, b2f1[kk - 4][n], acc2[n], 0, 0, 0);
        }

        // ---- bias + store fp32 ----
        const int ebase = g * 32;
        #pragma unroll
        for (int n = 0; n < 4; n++) {
            #pragma unroll
            for (int reg = 0; reg < 16; reg++) {
                const int row = (reg & 3) + 8 * (reg >> 2) + 4 * g2;
                out[(size_t)(ebase + row) * DD + n * 32 + r31] = acc2[n][reg] + b2v[n];
            }
        }

        snd = snd_n; rcv = rcv_n; g = gn;
    }
}

extern "C" void kernel_launch(void* const* d_in, const int* in_sizes, int n_in,
                              void* d_out, int out_size, void* d_ws, size_t ws_size,
                              hipStream_t stream) {
    const float* node_attr = (const float*)d_in[0];
    const int* eidx = (const int*)d_in[1];
    const float* edge_attr = (const float*)d_in[2];
    const float* w1 = (const float*)d_in[3];
    const float* b1 = (const float*)d_in[4];
    const float* w2 = (const float*)d_in[5];
    const float* b2 = (const float*)d_in[6];
    float* out = (float*)d_out;

    _Float16* w1t = (_Float16*)d_ws;            // 96KB swizzled
    _Float16* w2t = w1t + 384 * 128;            // 32KB linear

    static bool attr_set = false;
    if (!attr_set) {
        hipFuncSetAttribute((const void*)edge_mlp,
                            hipFuncAttributeMaxDynamicSharedMemorySize, 160 * 1024);
        attr_set = true;
    }

    prep_w<<<256, 256, 0, stream>>>(w1, w2, w1t, w2t);
    edge_mlp<<<256, 512, 160 * 1024, stream>>>(node_attr, eidx, edge_attr,
                                               w1t, b1, w2t, b2, out);
}

// Round 4
// 272.609 us; speedup vs baseline: 1.7028x; 1.7028x over previous
//
#include <hip/hip_runtime.h>

// EdgeBlock: out = relu(concat(node[snd], node[rcv], edge) @ w1 + b1) @ w2 + b2
// E=800000, N=50000, D=128. fp32 in/out, fp16 MFMA.
// Key change vs r2/r3: transaction-minimal gathers (2 rows/instr, 8x128B txns)
// staged through per-wave swizzled LDS; w2 fragment-major; nt hints on streams.

#define NE 800000
#define DD 128

typedef float f32x4v __attribute__((ext_vector_type(4)));
typedef float f32x16 __attribute__((ext_vector_type(16)));
typedef _Float16 f16x8 __attribute__((ext_vector_type(8)));
typedef _Float16 f16x4 __attribute__((ext_vector_type(4)));

__device__ __forceinline__ f16x4 cvt4(f32x4v v) {
    f16x4 r;
    r[0] = (_Float16)v[0]; r[1] = (_Float16)v[1];
    r[2] = (_Float16)v[2]; r[3] = (_Float16)v[3];
    return r;
}

// w1[384][128] -> w1t swizzled fp16: byte = col*768 + ((k*2) ^ ((col&15)<<4))   (96KB)
// w2[128][128] -> w2f fragment-major fp16: w2f[(kk2*128 + col)*8 + j] = w2[kk2*8+j][col] (32KB)
__global__ void prep_w(const float* __restrict__ w1, const float* __restrict__ w2,
                       _Float16* __restrict__ w1t, _Float16* __restrict__ w2f) {
    int i = blockIdx.x * 256 + threadIdx.x;   // 65536 total
    if (i < 384 * 128) {
        int col = i / 384;
        int k = i - col * 384;
        float v = w1[(size_t)k * 128 + col];
        int byteoff = col * 768 + ((k * 2) ^ ((col & 15) << 4));
        *(_Float16*)((char*)w1t + byteoff) = (_Float16)v;
    } else {
        int j = i - 384 * 128;                // 0..16383
        int kk2 = j >> 10;                    // 0..15
        int col = (j >> 3) & 127;
        int jj = j & 7;
        w2f[j] = (_Float16)w2[(size_t)(kk2 * 8 + jj) * 128 + col];
    }
}

__global__ __attribute__((amdgpu_flat_work_group_size(512, 512),
                          amdgpu_waves_per_eu(2, 2)))
void edge_mlp(
    const float* __restrict__ node_attr,
    const int* __restrict__ eidx,
    const float* __restrict__ edge_attr,
    const _Float16* __restrict__ w1t,   // swizzled, 96KB
    const float* __restrict__ b1,
    const _Float16* __restrict__ w2f,   // fragment-major, 32KB
    const float* __restrict__ b2,
    float* __restrict__ out) {
    extern __shared__ char lds[];   // [0,96K): w1t swz   [96K + wid*8K): A-seg / h per wave

    const int tid = threadIdx.x;
    const int wid = tid >> 6;
    const int lane = tid & 63;
    const int r31 = lane & 31;
    const int g2 = lane >> 5;
    const int sub = lane >> 5;     // row selector within pair
    const int c4 = lane & 31;      // float4 index within row

    // ---- stage w1t -> LDS (linear copy of pre-swizzled data) ----
    {
        const char* src = (const char*)w1t;
        #pragma unroll
        for (int i = 0; i < 12; i++) {
            int off = (tid + i * 512) * 16;   // 512*12*16B = 96KB
            *(f16x8*)(lds + off) = *(const f16x8*)(src + off);
        }
    }

    float b1v[4], b2v[4];
    #pragma unroll
    for (int n = 0; n < 4; n++) { b1v[n] = b1[n * 32 + r31]; b2v[n] = b2[n * 32 + r31]; }

    __syncthreads();

    char* ab = lds + 96 * 1024 + wid * 8192;   // 32 rows x 128 f16, swizzled
    const int ebase = blockIdx.x * 256 + wid * 32;

    const int sidx = eidx[ebase + r31];        // lanes 0..31 hold the tile's indices
    const int ridx = eidx[NE + ebase + r31];

    // ---- gather sender rows: 2 rows per instr, coalesced 128B segments ----
    f32x4v sv[16];
    #pragma unroll
    for (int i = 0; i < 16; i++) {
        int r = __shfl(sidx, 2 * i + sub);
        sv[i] = *(const f32x4v*)(node_attr + (size_t)r * DD + c4 * 4);
    }
    // write seg S to LDS (cvt f16, swizzled)
    #pragma unroll
    for (int i = 0; i < 16; i++) {
        const int row = 2 * i + sub;
        *(f16x4*)(ab + row * 256 + ((c4 * 8) ^ ((row & 15) << 4))) = cvt4(sv[i]);
    }

    // ---- issue receiver gathers (fly during seg-S MFMAs) ----
    f32x4v rv[16];
    #pragma unroll
    for (int i = 0; i < 16; i++) {
        int r = __shfl(ridx, 2 * i + sub);
        rv[i] = *(const f32x4v*)(node_attr + (size_t)r * DD + c4 * 4);
    }

    f32x16 acc[4] = {};
    const int xa = (r31 & 15) << 4;   // A-read swizzle

    // ---- consume seg 0 (sender) ----
    #pragma unroll
    for (int kk8 = 0; kk8 < 8; kk8++) {
        f16x8 a = *(const f16x8*)(ab + r31 * 256 + ((kk8 * 32 + g2 * 16) ^ xa));
        #pragma unroll
        for (int n = 0; n < 4; n++) {
            const int col = n * 32 + r31;
            f16x8 b = *(const f16x8*)(lds + col * 768 + (((0 * 8 + kk8) * 32 + g2 * 16) ^ ((col & 15) << 4)));
            acc[n] = __builtin_amdgcn_mfma_f32_32x32x16_f16(a, b, acc[n], 0, 0, 0);
        }
    }

    // write seg R, issue edge loads
    #pragma unroll
    for (int i = 0; i < 16; i++) {
        const int row = 2 * i + sub;
        *(f16x4*)(ab + row * 256 + ((c4 * 8) ^ ((row & 15) << 4))) = cvt4(rv[i]);
    }
    f32x4v ev[16];
    #pragma unroll
    for (int i = 0; i < 16; i++) {
        const int row = 2 * i + sub;
        ev[i] = __builtin_nontemporal_load(
            (const f32x4v*)(edge_attr + (size_t)(ebase + row) * DD + c4 * 4));
    }

    // ---- consume seg 1 (receiver) ----
    #pragma unroll
    for (int kk8 = 0; kk8 < 8; kk8++) {
        f16x8 a = *(const f16x8*)(ab + r31 * 256 + ((kk8 * 32 + g2 * 16) ^ xa));
        #pragma unroll
        for (int n = 0; n < 4; n++) {
            const int col = n * 32 + r31;
            f16x8 b = *(const f16x8*)(lds + col * 768 + (((1 * 8 + kk8) * 32 + g2 * 16) ^ ((col & 15) << 4)));
            acc[n] = __builtin_amdgcn_mfma_f32_32x32x16_f16(a, b, acc[n], 0, 0, 0);
        }
    }

    // write seg E
    #pragma unroll
    for (int i = 0; i < 16; i++) {
        const int row = 2 * i + sub;
        *(f16x4*)(ab + row * 256 + ((c4 * 8) ^ ((row & 15) << 4))) = cvt4(ev[i]);
    }

    // issue GEMM2 B-frags half 0 (independent of ab; hide under seg-E MFMAs + h-write)
    f16x8 b2fa[4][4];
    #pragma unroll
    for (int kk = 0; kk < 4; kk++)
        #pragma unroll
        for (int n = 0; n < 4; n++)
            b2fa[kk][n] = *(const f16x8*)(w2f + ((size_t)(kk * 2 + g2) * 128 + n * 32 + r31) * 8);

    // ---- consume seg 2 (edge) ----
    #pragma unroll
    for (int kk8 = 0; kk8 < 8; kk8++) {
        f16x8 a = *(const f16x8*)(ab + r31 * 256 + ((kk8 * 32 + g2 * 16) ^ xa));
        #pragma unroll
        for (int n = 0; n < 4; n++) {
            const int col = n * 32 + r31;
            f16x8 b = *(const f16x8*)(lds + col * 768 + (((2 * 8 + kk8) * 32 + g2 * 16) ^ ((col & 15) << 4)));
            acc[n] = __builtin_amdgcn_mfma_f32_32x32x16_f16(a, b, acc[n], 0, 0, 0);
        }
    }

    // ---- bias + relu, h -> same LDS buffer (seg data dead) ----
    #pragma unroll
    for (int n = 0; n < 4; n++) {
        const int col = n * 32 + r31;
        #pragma unroll
        for (int reg = 0; reg < 16; reg++) {
            const int row = (reg & 3) + 8 * (reg >> 2) + 4 * g2;
            float v = fmaxf(acc[n][reg] + b1v[n], 0.0f);
            *(_Float16*)(ab + row * 256 + ((col * 2) ^ ((row & 15) << 4))) = (_Float16)v;
        }
    }

    // ---------------- GEMM2: [32x128] @ [128x128] ----------------
    f32x16 acc2[4] = {};
    #pragma unroll
    for (int kk = 0; kk < 4; kk++) {
        f16x8 a = *(const f16x8*)(ab + r31 * 256 + ((kk * 32 + g2 * 16) ^ xa));
        #pragma unroll
        for (int n = 0; n < 4; n++)
            acc2[n] = __builtin_amdgcn_mfma_f32_32x32x16_f16(a, b2fa[kk][n], acc2[n], 0, 0, 0);
    }
    f16x8 b2fb[4][4];
    #pragma unroll
    for (int kk = 0; kk < 4; kk++)
        #pragma unroll
        for (int n = 0; n < 4; n++)
            b2fb[kk][n] = *(const f16x8*)(w2f + ((size_t)((kk + 4) * 2 + g2) * 128 + n * 32 + r31) * 8);
    #pragma unroll
    for (int kk = 4; kk < 8; kk++) {
        f16x8 a = *(const f16x8*)(ab + r31 * 256 + ((kk * 32 + g2 * 16) ^ xa));
        #pragma unroll
        for (int n = 0; n < 4; n++)
            acc2[n] = __builtin_amdgcn_mfma_f32_32x32x16_f16(a, b2fb[kk - 4][n], acc2[n], 0, 0, 0);
    }

    // ---- bias + store fp32 (coalesced 128B lines, nontemporal) ----
    #pragma unroll
    for (int n = 0; n < 4; n++) {
        #pragma unroll
        for (int reg = 0; reg < 16; reg++) {
            const int row = (reg & 3) + 8 * (reg >> 2) + 4 * g2;
            __builtin_nontemporal_store(acc2[n][reg] + b2v[n],
                out + (size_t)(ebase + row) * DD + n * 32 + r31);
        }
    }
}

extern "C" void kernel_launch(void* const* d_in, const int* in_sizes, int n_in,
                              void* d_out, int out_size, void* d_ws, size_t ws_size,
                              hipStream_t stream) {
    const float* node_attr = (const float*)d_in[0];
    const int* eidx = (const int*)d_in[1];
    const float* edge_attr = (const float*)d_in[2];
    const float* w1 = (const float*)d_in[3];
    const float* b1 = (const float*)d_in[4];
    const float* w2 = (const float*)d_in[5];
    const float* b2 = (const float*)d_in[6];
    float* out = (float*)d_out;

    _Float16* w1t = (_Float16*)d_ws;            // 96KB swizzled
    _Float16* w2f = w1t + 384 * 128;            // 32KB fragment-major

    hipFuncSetAttribute((const void*)edge_mlp,
                        hipFuncAttributeMaxDynamicSharedMemorySize, 160 * 1024);

    prep_w<<<256, 256, 0, stream>>>(w1, w2, w1t, w2f);
    edge_mlp<<<3125, 512, 160 * 1024, stream>>>(node_attr, eidx, edge_attr,
                                                w1t, b1, w2f, b2, out);
}